// Round 10
// baseline (838.716 us; speedup 1.0000x reference)
//
#include <hip/hip_runtime.h>
#include <math.h>
#include <float.h>

#define INPUT_DIM 1024
#define HIDDEN 128
#define KSEL 10

// scores kernel geometry: 4 waves, block tile 64 rows x 256 packed cols
// wave tile: 64 rows x 64 pc as 2m x 2n fragments of 32x32 (mfma_32x32x16)
#define BM 64
#define BK 64
#define KT (INPUT_DIM / BK)   // 16
#define STH 256
#define NSEL1 32              // stage-1 chunks per bag

typedef short short8 __attribute__((ext_vector_type(8)));
typedef float f32x4 __attribute__((ext_vector_type(4)));
typedef float f32x16 __attribute__((ext_vector_type(16)));

static __device__ __forceinline__ unsigned short f2bf(float f) {
    union { float f; unsigned u; } v; v.f = f;
    unsigned r = v.u + 0x7FFF + ((v.u >> 16) & 1);   // RNE
    return (unsigned short)(r >> 16);
}
static __device__ __forceinline__ float bf2f(unsigned short h) {
    union { unsigned u; float f; } v; v.u = ((unsigned)h) << 16;
    return v.f;
}
// split (a,b) -> packed hi word (truncation) + packed lo word (RNE of residual)
static __device__ __forceinline__ void split2(float a, float b, unsigned& hw, unsigned& lw) {
    unsigned ua = __float_as_uint(a) & 0xFFFF0000u;
    unsigned ub = __float_as_uint(b) & 0xFFFF0000u;
    float ra = a - __uint_as_float(ua);
    float rb = b - __uint_as_float(ub);
    asm("v_perm_b32 %0, %1, %2, %3" : "=v"(hw) : "v"(ub), "v"(ua), "s"(0x07060302));
    asm("v_cvt_pk_bf16_f32 %0, %1, %2" : "=v"(lw) : "v"(ra), "v"(rb));
}
static __device__ __forceinline__ float fast_tanh(float a) {
    float e = __expf(2.0f * a);
    return 1.0f - 2.0f / (e + 1.0f);
}
static __device__ __forceinline__ float fast_sigmoid(float a) {
    return 1.0f / (1.0f + __expf(-a));
}

// ---------------------------------------------------------------------------
// Repack W into 32x32x16 MFMA B-fragment order, split into bf16 hi/lo.
// pc = 2h + (0 Wv, 1 Wu). Fragment: lane l holds col pc = cg*32 + (l&31),
// k = kg*16 + (l>>5)*8 + e. Linear layout: [(kg*8 + cg)*64 + l]*8 + e.
// grid 512 blocks (bid = kg*8 + cg, kg 0..63, cg 0..7) x 64 threads.
// ---------------------------------------------------------------------------
__global__ __launch_bounds__(64) void repack_kernel(
    const float* __restrict__ Wv, const float* __restrict__ Wu,
    unsigned short* __restrict__ wp_hi, unsigned short* __restrict__ wp_lo)
{
    int bid = blockIdx.x;           // kg*8 + cg
    int l = threadIdx.x;
    int pc = (bid & 7) * 32 + (l & 31);
    int h = pc >> 1;
    const float* src = (pc & 1) ? Wu : Wv;
    int kbase = (bid >> 3) * 16 + (l >> 5) * 8;
    size_t off = ((size_t)bid * 64 + l) * 8;
    #pragma unroll
    for (int e = 0; e < 8; ++e) {
        float w = src[(size_t)(kbase + e) * HIDDEN + h];
        unsigned short hi = f2bf(w);
        unsigned short lo = f2bf(w - bf2f(hi));
        wp_hi[off + e] = hi;
        wp_lo[off + e] = lo;
    }
}

// ---------------------------------------------------------------------------
// Kernel 1: fused scores via split-bf16 3-term MFMA, 32x32x16 shape.
// 4 waves self-stage raw fp32 x via global_load_lds into a 2-buffer rotation
// (DMA 1 tile ahead). B-frags double-buffered at kg granularity (16 regs per
// set): every B-wait is either counted or drains the DMA after >=2 kg phases
// of flight. One raw barrier per K-step; next B-set flies across it.
// 32x32 shape halves MFMA instruction count and B register pressure vs
// 16x16, targeting a 3rd resident block per CU (3 waves/SIMD).
// ---------------------------------------------------------------------------
__global__ __launch_bounds__(STH) void scores_kernel(
    const float* __restrict__ x,
    const unsigned short* __restrict__ wp_hi, const unsigned short* __restrict__ wp_lo,
    const float* __restrict__ bv, const float* __restrict__ bu,
    const float* __restrict__ Ww, const float* __restrict__ bw,
    float* __restrict__ scores, float* __restrict__ atten, int N)
{
    __shared__ __align__(16) float buf[2][BM * BK];   // 32 KB (2 x 16 KB)
    __shared__ float partial[4][BM];                  // 1 KB

    const int tid = threadIdx.x;
    const int l = tid & 63;
    const int wc = tid >> 6;       // wave id 0..3 = wave-col group (2 cg each)
    const int b = blockIdx.y;
    const int i0 = blockIdx.x * BM;
    const float* xb = x + (size_t)b * N * INPUT_DIM;

    // Per-lane pre-swizzled global source pointers; wave stages rows
    // [wc*16, wc*16+16). LDS[row][c] holds global chunk (c ^ (row&7)).
    const float* gp[4];
    #pragma unroll
    for (int j = 0; j < 4; ++j) {
        int lr = wc * 16 + j * 4 + (l >> 4);         // local row
        int gi = min(i0 + lr, N - 1);                // clamp tail rows
        int csw = (l & 15) ^ (lr & 7);               // source chunk (involution)
        gp[j] = xb + (size_t)gi * INPUT_DIM + csw * 4;
    }

    f32x16 acc[2][2];
    #pragma unroll
    for (int m = 0; m < 2; ++m)
        #pragma unroll
        for (int n = 0; n < 2; ++n)
            #pragma unroll
            for (int r = 0; r < 16; ++r)
                acc[m][n][r] = 0.f;

#define STAGE(T) do { \
        float* _dst = &buf[(T) & 1][0]; \
        _Pragma("unroll") \
        for (int j = 0; j < 4; ++j) { \
            __builtin_amdgcn_global_load_lds( \
                (const __attribute__((address_space(1))) void*)gp[j], \
                (__attribute__((address_space(3))) void*)(_dst + (wc * 16 + j * 4) * BK), \
                16, 0, 0); \
            gp[j] += BK; \
        } \
    } while (0)

#define LOAD_B2(BH, BL, KG) do { \
        _Pragma("unroll") \
        for (int n = 0; n < 2; ++n) { \
            unsigned boff = (unsigned)((((KG) * 8 + wc * 2 + n) * 64 + l) * 8); \
            BH[n] = *(const short8*)(wp_hi + boff); \
            BL[n] = *(const short8*)(wp_lo + boff); \
        } \
    } while (0)

#define MFMA_KG(BUF, KG4, BH, BL) do { \
        __builtin_amdgcn_s_setprio(1); \
        _Pragma("unroll") \
        for (int m = 0; m < 2; ++m) { \
            int row = m * 32 + (l & 31); \
            int cb = (KG4) * 4 + (l >> 5) * 2; \
            int sw = l & 7;                      /* row&7 == l&7 here */ \
            f32x4 c0 = *(const f32x4*)(&BUF[row * BK + ((cb)     ^ sw) * 4]); \
            f32x4 c1 = *(const f32x4*)(&BUF[row * BK + ((cb + 1) ^ sw) * 4]); \
            union { short8 s; uint4 u; } Ah, Al; \
            split2(c0[0], c0[1], Ah.u.x, Al.u.x); \
            split2(c0[2], c0[3], Ah.u.y, Al.u.y); \
            split2(c1[0], c1[1], Ah.u.z, Al.u.z); \
            split2(c1[2], c1[3], Ah.u.w, Al.u.w); \
            _Pragma("unroll") \
            for (int n = 0; n < 2; ++n) { \
                acc[m][n] = __builtin_amdgcn_mfma_f32_32x32x16_bf16(Ah.s, BH[n], acc[m][n], 0, 0, 0); \
                acc[m][n] = __builtin_amdgcn_mfma_f32_32x32x16_bf16(Al.s, BH[n], acc[m][n], 0, 0, 0); \
                acc[m][n] = __builtin_amdgcn_mfma_f32_32x32x16_bf16(Ah.s, BL[n], acc[m][n], 0, 0, 0); \
            } \
        } \
        __builtin_amdgcn_s_setprio(0); \
    } while (0)

    short8 bhA[2], blA[2], bhB[2], blB[2];

    // prologue: B(kg0) first, then DMA tile 0; drain both, barrier.
    LOAD_B2(bhA, blA, 0);
    STAGE(0);
    asm volatile("s_waitcnt vmcnt(0)" ::: "memory");
    __builtin_amdgcn_s_barrier();

    for (int kt = 0; kt < KT; ++kt) {
        const float* BUF = &buf[kt & 1][0];
        const int kg = kt * 4;
        LOAD_B2(bhB, blB, kg + 1);                 // in flight
        if (kt + 1 < KT) STAGE(kt + 1);            // DMA next tile
        __builtin_amdgcn_sched_barrier(0);         // pin issue order above
        MFMA_KG(BUF, 0, bhA, blA);                 // counted wait (B1+DMA after)
        LOAD_B2(bhA, blA, kg + 2);
        MFMA_KG(BUF, 1, bhB, blB);                 // counted wait (DMA+B2 after)
        LOAD_B2(bhB, blB, kg + 3);
        MFMA_KG(BUF, 2, bhA, blA);                 // drains DMA (~2 kg flight, free)
        if (kt + 1 < KT) LOAD_B2(bhA, blA, kg + 4);
        MFMA_KG(BUF, 3, bhB, blB);                 // counted wait
        __builtin_amdgcn_s_barrier();              // raw: next B-set flies across
    }

#undef STAGE
#undef LOAD_B2
#undef MFMA_KG

    // ---- epilogue: gate, project, row-reduce (32x32 C/D layout:
    // col = lane&31, row = (reg&3) + 8*(reg>>2) + 4*(lane>>5)) ----
    float bvv[2], buu[2], www[2];
    #pragma unroll
    for (int n = 0; n < 2; ++n) {
        int h = (wc * 64 + n * 32 + (l & 31)) >> 1;
        bvv[n] = bv[h]; buu[n] = bu[h]; www[n] = Ww[h];
    }
    const bool isV = ((l & 1) == 0);

    #pragma unroll
    for (int m = 0; m < 2; ++m) {
        float cs[16];
        #pragma unroll
        for (int r = 0; r < 16; ++r) cs[r] = 0.f;
        #pragma unroll
        for (int n = 0; n < 2; ++n) {
            #pragma unroll
            for (int r = 0; r < 16; ++r) {
                float v = acc[m][n][r];
                float u = __shfl_xor(v, 1, 64);     // partner col (U pre-act)
                if (isV)
                    cs[r] += fast_tanh(v + bvv[n]) * fast_sigmoid(u + buu[n]) * www[n];
            }
        }
        #pragma unroll
        for (int r = 0; r < 16; ++r) {
            #pragma unroll
            for (int off = 1; off < 32; off <<= 1)
                cs[r] += __shfl_xor(cs[r], off, 64);
        }
        if ((l & 31) == 0) {
            #pragma unroll
            for (int r = 0; r < 16; ++r) {
                int row = m * 32 + (r & 3) + 8 * (r >> 2) + 4 * (l >> 5);
                partial[wc][row] = cs[r];
            }
        }
    }
    __syncthreads();

    if (tid < BM) {
        int gi = i0 + tid;
        if (gi < N) {
            float s = partial[0][tid] + partial[1][tid] + partial[2][tid] + partial[3][tid] + bw[0];
            scores[(size_t)b * N + gi] = s;
            atten[(size_t)b * N + gi] = 0.0f;
        }
    }
}

// ---------------------------------------------------------------------------
// Kernel 2a: per (chunk, bag) local top-10 / bottom-10. 1 wave per block.
// cand layout: [b][r][0..9 top desc, 10..19 bottom asc]
// ---------------------------------------------------------------------------
__global__ __launch_bounds__(64) void select1_kernel(
    const float* __restrict__ scores, float* __restrict__ cv, int* __restrict__ ci,
    int N, int CH)
{
    const int r = blockIdx.x, b = blockIdx.y;
    const int tid = threadIdx.x;
    const float* s = scores + (size_t)b * N;
    const int start = r * CH;
    const int end = min(N, start + CH);

    float tv[KSEL]; int ti[KSEL];
    float lv[KSEL]; int li[KSEL];
    #pragma unroll
    for (int j = 0; j < KSEL; ++j) { tv[j] = -FLT_MAX; ti[j] = -1; lv[j] = FLT_MAX; li[j] = -1; }

    for (int i = start + tid; i < end; i += 64) {
        float v = s[i];
        if (v > tv[KSEL-1]) {
            #pragma unroll
            for (int j = KSEL-1; j >= 1; --j) {
                if (v > tv[j-1])      { tv[j] = tv[j-1]; ti[j] = ti[j-1]; }
                else if (v > tv[j])   { tv[j] = v;       ti[j] = i;       }
            }
            if (v > tv[0]) { tv[0] = v; ti[0] = i; }
        }
        if (v < lv[KSEL-1]) {
            #pragma unroll
            for (int j = KSEL-1; j >= 1; --j) {
                if (v < lv[j-1])      { lv[j] = lv[j-1]; li[j] = li[j-1]; }
                else if (v < lv[j])   { lv[j] = v;       li[j] = i;       }
            }
            if (v < lv[0]) { lv[0] = v; li[0] = i; }
        }
    }

    size_t base = ((size_t)b * NSEL1 + r) * 2 * KSEL;
    for (int rd = 0; rd < KSEL; ++rd) {
        float v = tv[0]; int who = tid;
        #pragma unroll
        for (int off = 32; off > 0; off >>= 1) {
            float ov = __shfl_down(v, off, 64);
            int ow = __shfl_down(who, off, 64);
            if (ov > v) { v = ov; who = ow; }
        }
        int bwho = __shfl(who, 0, 64);
        if (tid == bwho) {
            cv[base + rd] = tv[0]; ci[base + rd] = ti[0];
            #pragma unroll
            for (int j = 0; j < KSEL-1; ++j) { tv[j] = tv[j+1]; ti[j] = ti[j+1]; }
            tv[KSEL-1] = -FLT_MAX;
        }
    }
    for (int rd = 0; rd < KSEL; ++rd) {
        float v = lv[0]; int who = tid;
        #pragma unroll
        for (int off = 32; off > 0; off >>= 1) {
            float ov = __shfl_down(v, off, 64);
            int ow = __shfl_down(who, off, 64);
            if (ov < v) { v = ov; who = ow; }
        }
        int bwho = __shfl(who, 0, 64);
        if (tid == bwho) {
            cv[base + KSEL + rd] = lv[0]; ci[base + KSEL + rd] = li[0];
            #pragma unroll
            for (int j = 0; j < KSEL-1; ++j) { lv[j] = lv[j+1]; li[j] = li[j+1]; }
            lv[KSEL-1] = FLT_MAX;
        }
    }
}

// ---------------------------------------------------------------------------
// Kernel 2b (fused with Z): per bag merge candidates, softmax, scatter atten,
// then weighted gather Z[b,:] with all 256 threads.
// ---------------------------------------------------------------------------
__global__ __launch_bounds__(256) void select2_z_kernel(
    const float* __restrict__ cv, const int* __restrict__ ci,
    const float* __restrict__ x,
    float* __restrict__ atten, float* __restrict__ Z, int N)
{
    const int b = blockIdx.x;
    const int tid = threadIdx.x;
    __shared__ float selv[2*KSEL]; __shared__ int seli[2*KSEL];
    __shared__ float selw[2*KSEL];

    if (tid < 64) {
        float tv[KSEL]; int ti[KSEL];
        float lv[KSEL]; int li[KSEL];
        #pragma unroll
        for (int j = 0; j < KSEL; ++j) { tv[j] = -FLT_MAX; ti[j] = -1; lv[j] = FLT_MAX; li[j] = -1; }

        for (int c = tid; c < NSEL1 * KSEL; c += 64) {
            int rr = c / KSEL, jj = c % KSEL;
            size_t base = ((size_t)b * NSEL1 + rr) * 2 * KSEL;
            {
                float v = cv[base + jj]; int idx = ci[base + jj];
                if (v > tv[KSEL-1]) {
                    #pragma unroll
                    for (int j = KSEL-1; j >= 1; --j) {
                        if (v > tv[j-1])      { tv[j] = tv[j-1]; ti[j] = ti[j-1]; }
                        else if (v > tv[j])   { tv[j] = v;       ti[j] = idx;     }
                    }
                    if (v > tv[0]) { tv[0] = v; ti[0] = idx; }
                }
            }
            {
                float v = cv[base + KSEL + jj]; int idx = ci[base + KSEL + jj];
                if (v < lv[KSEL-1]) {
                    #pragma unroll
                    for (int j = KSEL-1; j >= 1; --j) {
                        if (v < lv[j-1])      { lv[j] = lv[j-1]; li[j] = li[j-1]; }
                        else if (v < lv[j])   { lv[j] = v;       li[j] = idx;     }
                    }
                    if (v < lv[0]) { lv[0] = v; li[0] = idx; }
                }
            }
        }

        for (int rd = 0; rd < KSEL; ++rd) {
            float v = tv[0]; int who = tid;
            #pragma unroll
            for (int off = 32; off > 0; off >>= 1) {
                float ov = __shfl_down(v, off, 64);
                int ow = __shfl_down(who, off, 64);
                if (ov > v) { v = ov; who = ow; }
            }
            int bwho = __shfl(who, 0, 64);
            if (tid == bwho) {
                selv[rd] = tv[0]; seli[rd] = ti[0];
                #pragma unroll
                for (int j = 0; j < KSEL-1; ++j) { tv[j] = tv[j+1]; ti[j] = ti[j+1]; }
                tv[KSEL-1] = -FLT_MAX;
            }
        }
        for (int rd = 0; rd < KSEL; ++rd) {
            float v = lv[0]; int who = tid;
            #pragma unroll
            for (int off = 32; off > 0; off >>= 1) {
                float ov = __shfl_down(v, off, 64);
                int ow = __shfl_down(who, off, 64);
                if (ov < v) { v = ov; who = ow; }
            }
            int bwho = __shfl(who, 0, 64);
            if (tid == bwho) {
                selv[KSEL + rd] = lv[0]; seli[KSEL + rd] = li[0];
                #pragma unroll
                for (int j = 0; j < KSEL-1; ++j) { lv[j] = lv[j+1]; li[j] = li[j+1]; }
                lv[KSEL-1] = FLT_MAX;
            }
        }
    }
    __syncthreads();

    if (tid == 0) {
        float m = -FLT_MAX;
        #pragma unroll
        for (int j = 0; j < 2*KSEL; ++j) m = fmaxf(m, selv[j]);
        float e[2*KSEL]; float sum = 0.f;
        #pragma unroll
        for (int j = 0; j < 2*KSEL; ++j) { e[j] = expf(selv[j] - m); sum += e[j]; }
        float inv = 1.0f / sum;
        #pragma unroll
        for (int j = 0; j < 2*KSEL; ++j) {
            float w = e[j] * inv;
            selw[j] = w;
            atten[(size_t)b * N + seli[j]] = w;
        }
    }
    __syncthreads();

    // Z gather: 256 threads x float4 = 1024 floats
    float4 acc = make_float4(0.f, 0.f, 0.f, 0.f);
    #pragma unroll
    for (int j = 0; j < 2*KSEL; ++j) {
        int idx = seli[j];
        float w = selw[j];
        const float4* xr = (const float4*)(x + ((size_t)b * N + idx) * INPUT_DIM);
        float4 v = xr[tid];
        acc.x = fmaf(w, v.x, acc.x);
        acc.y = fmaf(w, v.y, acc.y);
        acc.z = fmaf(w, v.z, acc.z);
        acc.w = fmaf(w, v.w, acc.w);
    }
    ((float4*)(Z + (size_t)b * INPUT_DIM))[tid] = acc;
}

extern "C" void kernel_launch(void* const* d_in, const int* in_sizes, int n_in,
                              void* d_out, int out_size, void* d_ws, size_t ws_size,
                              hipStream_t stream)
{
    const float* x  = (const float*)d_in[0];
    const float* Wv = (const float*)d_in[1];
    const float* bv = (const float*)d_in[2];
    const float* Wu = (const float*)d_in[3];
    const float* bu = (const float*)d_in[4];
    const float* Ww = (const float*)d_in[5];
    const float* bw = (const float*)d_in[6];

    const int B = 8;
    const int N = in_sizes[0] / (B * INPUT_DIM);   // 50000

    float* Z = (float*)d_out;                              // [B,1024]
    float* atten = (float*)d_out + (size_t)B * INPUT_DIM;  // [B,N]

    // workspace layout
    char* p = (char*)d_ws;
    float* scores = (float*)p;                  p += (size_t)B * N * sizeof(float);
    unsigned short* wp_hi = (unsigned short*)p; p += (size_t)INPUT_DIM * 256 * sizeof(unsigned short);
    unsigned short* wp_lo = (unsigned short*)p; p += (size_t)INPUT_DIM * 256 * sizeof(unsigned short);
    float* cand_v = (float*)p;                  p += (size_t)B * NSEL1 * 2 * KSEL * sizeof(float);
    int* cand_i = (int*)p;                      p += (size_t)B * NSEL1 * 2 * KSEL * sizeof(int);

    repack_kernel<<<512, 64, 0, stream>>>(Wv, Wu, wp_hi, wp_lo);

    dim3 g1((N + BM - 1) / BM, B);
    scores_kernel<<<g1, STH, 0, stream>>>(x, wp_hi, wp_lo, bv, bu, Ww, bw, scores, atten, N);

    int CH = (N + NSEL1 - 1) / NSEL1;
    dim3 g2(NSEL1, B);
    select1_kernel<<<g2, 64, 0, stream>>>(scores, cand_v, cand_i, N, CH);
    select2_z_kernel<<<B, 256, 0, stream>>>(cand_v, cand_i, x, atten, Z, N);
}

// Round 11
// 762.879 us; speedup vs baseline: 1.0994x; 1.0994x over previous
//
#include <hip/hip_runtime.h>
#include <math.h>
#include <float.h>

#define INPUT_DIM 1024
#define HIDDEN 128
#define KSEL 10
#define KC 12                 // candidates per side (containment margin 2)

// scores kernel geometry: 8 waves, block tile 32 rows x 256 packed cols,
// wave tile 32 rows x 32 pc (2m x 2n fragments of 16x16)
#define BM 32
#define BK 64
#define KT (INPUT_DIM / BK)   // 16
#define STH 512
#define NSEL1 32              // stage-1 chunks per bag

typedef short short8 __attribute__((ext_vector_type(8)));
typedef float f32x4 __attribute__((ext_vector_type(4)));

static __device__ __forceinline__ unsigned short f2bf(float f) {
    union { float f; unsigned u; } v; v.f = f;
    unsigned r = v.u + 0x7FFF + ((v.u >> 16) & 1);   // RNE
    return (unsigned short)(r >> 16);
}
// split (a,b) -> packed hi word (truncation) + packed lo word (RNE of residual)
// xh + xl == x to ~2^-16 relative, so xh*wh + xl*wh == x*wh (exact in x).
static __device__ __forceinline__ void split2(float a, float b, unsigned& hw, unsigned& lw) {
    unsigned ua = __float_as_uint(a) & 0xFFFF0000u;
    unsigned ub = __float_as_uint(b) & 0xFFFF0000u;
    float ra = a - __uint_as_float(ua);
    float rb = b - __uint_as_float(ub);
    asm("v_perm_b32 %0, %1, %2, %3" : "=v"(hw) : "v"(ub), "v"(ua), "s"(0x07060302));
    asm("v_cvt_pk_bf16_f32 %0, %1, %2" : "=v"(lw) : "v"(ra), "v"(rb));
}
static __device__ __forceinline__ float fast_tanh(float a) {
    float e = __expf(2.0f * a);
    return 1.0f - 2.0f / (e + 1.0f);
}
static __device__ __forceinline__ float fast_sigmoid(float a) {
    return 1.0f / (1.0f + __expf(-a));
}

// ---------------------------------------------------------------------------
// Repack W into MFMA B-fragment order (16x16x32), bf16 RNE (hi only — the
// 2-term scheme computes exact x (dot) w_hi; w_lo handled by exact rescore).
// pc = 2h + (0 Wv, 1 Wu). wp[kg][cg][lane][e]: k = kg*32+(lane>>4)*8+e,
// pc = cg*16+(lane&15). grid 512 (= 32 kg x 16 cg) x 64.
// ---------------------------------------------------------------------------
__global__ __launch_bounds__(64) void repack_kernel(
    const float* __restrict__ Wv, const float* __restrict__ Wu,
    unsigned short* __restrict__ wp_hi)
{
    int bid = blockIdx.x;           // kg*16 + cg
    int l = threadIdx.x;
    int pc = (bid & 15) * 16 + (l & 15);
    int h = pc >> 1;
    const float* src = (pc & 1) ? Wu : Wv;
    int kbase = (bid >> 4) * 32 + (l >> 4) * 8;
    size_t off = ((size_t)bid * 64 + l) * 8;
    #pragma unroll
    for (int e = 0; e < 8; ++e)
        wp_hi[off + e] = f2bf(src[(size_t)(kbase + e) * HIDDEN + h]);
}

// ---------------------------------------------------------------------------
// Kernel 1: approx scores = x (dot) w_hi via 2-term split-bf16 MFMA.
// 8 waves; wave w: pc [w*32, w*32+32) (cg 2w, 2w+1), rows shared 0..31.
// acc = 16 VGPR/wave -> target 4 waves/SIMD (2 blocks/CU, 16 waves).
// x staged raw fp32 via global_load_lds, 3-buffer rotation, DMA 2 tiles
// ahead; every vmcnt wait is counted or drains a DMA with >=2 MFMA-block
// flight (round-9 FIFO discipline). One raw barrier per K-step.
// ---------------------------------------------------------------------------
__global__ __launch_bounds__(STH) void scores_kernel(
    const float* __restrict__ x, const unsigned short* __restrict__ wp_hi,
    const float* __restrict__ bv, const float* __restrict__ bu,
    const float* __restrict__ Ww, const float* __restrict__ bw,
    float* __restrict__ scores, float* __restrict__ atten, int N)
{
    __shared__ __align__(16) float buf[3][BM * BK];   // 24 KB (3 x 8 KB)
    __shared__ float partial[8][BM];                  // 1 KB

    const int tid = threadIdx.x;
    const int l = tid & 63;
    const int w = tid >> 6;        // wave id 0..7
    const int b = blockIdx.y;
    const int i0 = blockIdx.x * BM;
    const float* xb = x + (size_t)b * N * INPUT_DIM;

    // staging: wave w stages rows [w*4, w*4+4); lane l -> row w*4+(l>>4),
    // source chunk (l&15)^(row&7) (involution) -> LDS[row][c] = g[row][c^(row&7)]
    {
    }
    int lr = w * 4 + (l >> 4);
    int gi = min(i0 + lr, N - 1);                 // clamp tail rows (never written out)
    int csw = (l & 15) ^ (lr & 7);
    const float* gp = xb + (size_t)gi * INPUT_DIM + csw * 4;

    f32x4 acc[2][2];
    #pragma unroll
    for (int m = 0; m < 2; ++m)
        #pragma unroll
        for (int n = 0; n < 2; ++n)
            acc[m][n] = (f32x4){0.f, 0.f, 0.f, 0.f};

#define STAGE(T) do { \
        __builtin_amdgcn_global_load_lds( \
            (const __attribute__((address_space(1))) void*)gp, \
            (__attribute__((address_space(3))) void*)(&buf[(T) % 3][w * 4 * BK]), \
            16, 0, 0); \
        gp += BK; \
    } while (0)

#define LOAD_B(BH, KG) do { \
        _Pragma("unroll") \
        for (int n = 0; n < 2; ++n) { \
            unsigned boff = (unsigned)((((KG) * 16 + w * 2 + n) * 64 + l) * 8); \
            BH[n] = *(const short8*)(wp_hi + boff); \
        } \
    } while (0)

#define MFMA_KS(BUF, KS, BH) do { \
        __builtin_amdgcn_s_setprio(1); \
        _Pragma("unroll") \
        for (int m = 0; m < 2; ++m) { \
            int row = m * 16 + (l & 15); \
            int k4 = (KS) * 8 + (l >> 4) * 2; \
            int sw = l & 7;                      /* row&7 == l&7 */ \
            f32x4 c0 = *(const f32x4*)(&BUF[row * BK + ((k4)     ^ sw) * 4]); \
            f32x4 c1 = *(const f32x4*)(&BUF[row * BK + ((k4 + 1) ^ sw) * 4]); \
            union { short8 s; uint4 u; } Ah, Al; \
            split2(c0[0], c0[1], Ah.u.x, Al.u.x); \
            split2(c0[2], c0[3], Ah.u.y, Al.u.y); \
            split2(c1[0], c1[1], Ah.u.z, Al.u.z); \
            split2(c1[2], c1[3], Ah.u.w, Al.u.w); \
            _Pragma("unroll") \
            for (int n = 0; n < 2; ++n) { \
                acc[m][n] = __builtin_amdgcn_mfma_f32_16x16x32_bf16(Ah.s, BH[n], acc[m][n], 0, 0, 0); \
                acc[m][n] = __builtin_amdgcn_mfma_f32_16x16x32_bf16(Al.s, BH[n], acc[m][n], 0, 0, 0); \
            } \
        } \
        __builtin_amdgcn_s_setprio(0); \
    } while (0)

    short8 bhA[2], bhB[2];

    // prologue: B(0,0), tile0 DMA, drain both; tile1 DMA flies across barrier.
    LOAD_B(bhA, 0);
    STAGE(0);
    asm volatile("s_waitcnt vmcnt(0)" ::: "memory");
    STAGE(1);
    __builtin_amdgcn_s_barrier();

    for (int kt = 0; kt < KT; ++kt) {
        const float* BUF = &buf[kt % 3][0];
        LOAD_B(bhB, kt * 2 + 1);
        if (kt + 2 < KT) STAGE(kt + 2);
        __builtin_amdgcn_sched_barrier(0);        // pin issue order above MFMA
        MFMA_KS(BUF, 0, bhA);                     // bhA-wait drains DMA(kt+1): >=2 blocks flight
        if (kt + 1 < KT) LOAD_B(bhA, kt * 2 + 2);
        MFMA_KS(BUF, 1, bhB);                     // counted: DMA(kt+2)+bhA stay in flight
        __builtin_amdgcn_s_barrier();             // raw: loads fly across
    }

#undef STAGE
#undef LOAD_B
#undef MFMA_KS

    // ---- epilogue: gate, project, row-reduce ----
    float bvv[2], buu[2], www[2];
    #pragma unroll
    for (int n = 0; n < 2; ++n) {
        int h = ((w * 2 + n) * 16 + (l & 15)) >> 1;
        bvv[n] = bv[h]; buu[n] = bu[h]; www[n] = Ww[h];
    }
    const bool isV = ((l & 1) == 0);

    #pragma unroll
    for (int m = 0; m < 2; ++m) {
        float cs[4] = {0.f, 0.f, 0.f, 0.f};
        #pragma unroll
        for (int n = 0; n < 2; ++n) {
            #pragma unroll
            for (int r = 0; r < 4; ++r) {
                float v = acc[m][n][r];
                float u = __shfl_xor(v, 1, 64);     // partner col (U pre-act)
                if (isV)
                    cs[r] += fast_tanh(v + bvv[n]) * fast_sigmoid(u + buu[n]) * www[n];
            }
        }
        #pragma unroll
        for (int r = 0; r < 4; ++r) {
            #pragma unroll
            for (int off = 1; off < 16; off <<= 1)
                cs[r] += __shfl_xor(cs[r], off, 64);
        }
        if ((l & 15) == 0) {
            #pragma unroll
            for (int r = 0; r < 4; ++r)
                partial[w][m * 16 + (l >> 4) * 4 + r] = cs[r];
        }
    }
    __syncthreads();

    if (tid < BM) {
        int gi2 = i0 + tid;
        if (gi2 < N) {
            float s = bw[0];
            #pragma unroll
            for (int ww2 = 0; ww2 < 8; ++ww2) s += partial[ww2][tid];
            scores[(size_t)b * N + gi2] = s;
            atten[(size_t)b * N + gi2] = 0.0f;
        }
    }
}

// ---------------------------------------------------------------------------
// Kernel 2a: per (chunk, bag) approx top-12 / bottom-12. 1 wave per block.
// cand layout: [b][chunk][0..11 top desc, 12..23 bottom asc]
// ---------------------------------------------------------------------------
__global__ __launch_bounds__(64) void select1_kernel(
    const float* __restrict__ scores, float* __restrict__ cv, int* __restrict__ ci,
    int N, int CH)
{
    const int r = blockIdx.x, b = blockIdx.y;
    const int tid = threadIdx.x;
    const float* s = scores + (size_t)b * N;
    const int start = r * CH;
    const int end = min(N, start + CH);

    float tv[KC]; int ti[KC];
    float lv[KC]; int li[KC];
    #pragma unroll
    for (int j = 0; j < KC; ++j) { tv[j] = -FLT_MAX; ti[j] = -1; lv[j] = FLT_MAX; li[j] = -1; }

    for (int i = start + tid; i < end; i += 64) {
        float v = s[i];
        if (v > tv[KC-1]) {
            #pragma unroll
            for (int j = KC-1; j >= 1; --j) {
                if (v > tv[j-1])      { tv[j] = tv[j-1]; ti[j] = ti[j-1]; }
                else if (v > tv[j])   { tv[j] = v;       ti[j] = i;       }
            }
            if (v > tv[0]) { tv[0] = v; ti[0] = i; }
        }
        if (v < lv[KC-1]) {
            #pragma unroll
            for (int j = KC-1; j >= 1; --j) {
                if (v < lv[j-1])      { lv[j] = lv[j-1]; li[j] = li[j-1]; }
                else if (v < lv[j])   { lv[j] = v;       li[j] = i;       }
            }
            if (v < lv[0]) { lv[0] = v; li[0] = i; }
        }
    }

    size_t base = ((size_t)b * NSEL1 + r) * 2 * KC;
    for (int rd = 0; rd < KC; ++rd) {
        float v = tv[0]; int who = tid;
        #pragma unroll
        for (int off = 32; off > 0; off >>= 1) {
            float ov = __shfl_down(v, off, 64);
            int ow = __shfl_down(who, off, 64);
            if (ov > v) { v = ov; who = ow; }
        }
        int bwho = __shfl(who, 0, 64);
        if (tid == bwho) {
            cv[base + rd] = tv[0]; ci[base + rd] = ti[0];
            #pragma unroll
            for (int j = 0; j < KC-1; ++j) { tv[j] = tv[j+1]; ti[j] = ti[j+1]; }
            tv[KC-1] = -FLT_MAX;
        }
    }
    for (int rd = 0; rd < KC; ++rd) {
        float v = lv[0]; int who = tid;
        #pragma unroll
        for (int off = 32; off > 0; off >>= 1) {
            float ov = __shfl_down(v, off, 64);
            int ow = __shfl_down(who, off, 64);
            if (ov < v) { v = ov; who = ow; }
        }
        int bwho = __shfl(who, 0, 64);
        if (tid == bwho) {
            cv[base + KC + rd] = lv[0]; ci[base + KC + rd] = li[0];
            #pragma unroll
            for (int j = 0; j < KC-1; ++j) { lv[j] = lv[j+1]; li[j] = li[j+1]; }
            lv[KC-1] = FLT_MAX;
        }
    }
}

// ---------------------------------------------------------------------------
// Kernel 2b: per bag, merge 32x12 per side -> global approx top-12/bottom-12.
// Outputs candidate INDICES only: cand_idx[b][0..11 top, 12..23 bottom].
// ---------------------------------------------------------------------------
__global__ __launch_bounds__(64) void select2_kernel(
    const float* __restrict__ cv, const int* __restrict__ ci,
    int* __restrict__ cand_idx)
{
    const int b = blockIdx.x;
    const int tid = threadIdx.x;

    float tv[KC]; int ti[KC];
    float lv[KC]; int li[KC];
    #pragma unroll
    for (int j = 0; j < KC; ++j) { tv[j] = -FLT_MAX; ti[j] = -1; lv[j] = FLT_MAX; li[j] = -1; }

    for (int c = tid; c < NSEL1 * KC; c += 64) {
        int rr = c / KC, jj = c % KC;
        size_t base = ((size_t)b * NSEL1 + rr) * 2 * KC;
        {
            float v = cv[base + jj]; int idx = ci[base + jj];
            if (v > tv[KC-1]) {
                #pragma unroll
                for (int j = KC-1; j >= 1; --j) {
                    if (v > tv[j-1])      { tv[j] = tv[j-1]; ti[j] = ti[j-1]; }
                    else if (v > tv[j])   { tv[j] = v;       ti[j] = idx;     }
                }
                if (v > tv[0]) { tv[0] = v; ti[0] = idx; }
            }
        }
        {
            float v = cv[base + KC + jj]; int idx = ci[base + KC + jj];
            if (v < lv[KC-1]) {
                #pragma unroll
                for (int j = KC-1; j >= 1; --j) {
                    if (v < lv[j-1])      { lv[j] = lv[j-1]; li[j] = li[j-1]; }
                    else if (v < lv[j])   { lv[j] = v;       li[j] = idx;     }
                }
                if (v < lv[0]) { lv[0] = v; li[0] = idx; }
            }
        }
    }

    for (int rd = 0; rd < KC; ++rd) {
        float v = tv[0]; int who = tid;
        #pragma unroll
        for (int off = 32; off > 0; off >>= 1) {
            float ov = __shfl_down(v, off, 64);
            int ow = __shfl_down(who, off, 64);
            if (ov > v) { v = ov; who = ow; }
        }
        int bwho = __shfl(who, 0, 64);
        if (tid == bwho) {
            cand_idx[b * 2 * KC + rd] = ti[0];
            #pragma unroll
            for (int j = 0; j < KC-1; ++j) { tv[j] = tv[j+1]; ti[j] = ti[j+1]; }
            tv[KC-1] = -FLT_MAX;
        }
    }
    for (int rd = 0; rd < KC; ++rd) {
        float v = lv[0]; int who = tid;
        #pragma unroll
        for (int off = 32; off > 0; off >>= 1) {
            float ov = __shfl_down(v, off, 64);
            int ow = __shfl_down(who, off, 64);
            if (ov < v) { v = ov; who = ow; }
        }
        int bwho = __shfl(who, 0, 64);
        if (tid == bwho) {
            cand_idx[b * 2 * KC + KC + rd] = li[0];
            #pragma unroll
            for (int j = 0; j < KC-1; ++j) { lv[j] = lv[j+1]; li[j] = li[j+1]; }
            lv[KC-1] = FLT_MAX;
        }
    }
}

// ---------------------------------------------------------------------------
// Kernel 3: exact fp32 rescore of each candidate row. Block = (cand j, bag b).
// thread t: h = t>>1, V-dot (even) / U-dot (odd); x row staged in LDS.
// ---------------------------------------------------------------------------
__global__ __launch_bounds__(256) void rescore_kernel(
    const float* __restrict__ x,
    const float* __restrict__ Wv, const float* __restrict__ bv,
    const float* __restrict__ Wu, const float* __restrict__ bu,
    const float* __restrict__ Ww, const float* __restrict__ bw,
    const int* __restrict__ cand_idx, float* __restrict__ cand_score, int N)
{
    const int j = blockIdx.x, b = blockIdx.y;
    const int tid = threadIdx.x;
    __shared__ float xs[INPUT_DIM];
    __shared__ float sp[4];

    int idx = cand_idx[b * 2 * KC + j];
    const float* xr = x + ((size_t)b * N + idx) * INPUT_DIM;
    *(float4*)(&xs[tid * 4]) = *(const float4*)(&xr[tid * 4]);
    __syncthreads();

    const int h = tid >> 1;
    const int isU = tid & 1;
    const float* W = isU ? Wu : Wv;
    float s = 0.f;
    #pragma unroll 8
    for (int k = 0; k < INPUT_DIM; ++k)
        s = fmaf(xs[k], W[(size_t)k * HIDDEN + h], s);

    float other = __shfl_xor(s, 1, 64);
    float g = 0.f;
    if (!isU) {
        float vv = tanhf(s + bv[h]);
        float uu = 1.0f / (1.0f + expf(-(other + bu[h])));
        g = vv * uu * Ww[h];
    }
    #pragma unroll
    for (int off = 1; off < 64; off <<= 1) g += __shfl_xor(g, off, 64);
    if ((tid & 63) == 0) sp[tid >> 6] = g;
    __syncthreads();
    if (tid == 0)
        cand_score[b * 2 * KC + j] = sp[0] + sp[1] + sp[2] + sp[3] + bw[0];
}

// ---------------------------------------------------------------------------
// Kernel 4: per bag, exact top-10 set (from top-12) + bottom-10 set (from
// bottom-12), exact softmax over 20, scatter atten, weighted gather Z.
// ---------------------------------------------------------------------------
__global__ __launch_bounds__(256) void final_kernel(
    const float* __restrict__ x, const int* __restrict__ cand_idx,
    const float* __restrict__ cand_score,
    float* __restrict__ atten, float* __restrict__ Z, int N)
{
    const int b = blockIdx.x;
    const int tid = threadIdx.x;
    __shared__ int fidx[2 * KSEL];
    __shared__ float fw[2 * KSEL];

    if (tid == 0) {
        float cs[2 * KC]; int ciX[2 * KC]; bool used[2 * KC];
        #pragma unroll
        for (int j2 = 0; j2 < 2 * KC; ++j2) {
            cs[j2] = cand_score[b * 2 * KC + j2];
            ciX[j2] = cand_idx[b * 2 * KC + j2];
            used[j2] = false;
        }
        float fs[2 * KSEL];
        for (int r = 0; r < KSEL; ++r) {        // exact top-10 among top-12
            int best = -1; float bvv = -FLT_MAX;
            for (int j2 = 0; j2 < KC; ++j2)
                if (!used[j2] && cs[j2] > bvv) { bvv = cs[j2]; best = j2; }
            used[best] = true; fidx[r] = ciX[best]; fs[r] = bvv;
        }
        for (int r = 0; r < KSEL; ++r) {        // exact bottom-10 among bottom-12
            int best = -1; float bvv = FLT_MAX;
            for (int j2 = KC; j2 < 2 * KC; ++j2)
                if (!used[j2] && cs[j2] < bvv) { bvv = cs[j2]; best = j2; }
            used[best] = true; fidx[KSEL + r] = ciX[best]; fs[KSEL + r] = bvv;
        }
        float m = -FLT_MAX;
        for (int j2 = 0; j2 < 2 * KSEL; ++j2) m = fmaxf(m, fs[j2]);
        float e[2 * KSEL], sum = 0.f;
        for (int j2 = 0; j2 < 2 * KSEL; ++j2) { e[j2] = expf(fs[j2] - m); sum += e[j2]; }
        float inv = 1.0f / sum;
        for (int j2 = 0; j2 < 2 * KSEL; ++j2) {
            fw[j2] = e[j2] * inv;
            atten[(size_t)b * N + fidx[j2]] = fw[j2];
        }
    }
    __syncthreads();

    float4 acc = make_float4(0.f, 0.f, 0.f, 0.f);
    #pragma unroll
    for (int j2 = 0; j2 < 2 * KSEL; ++j2) {
        int idx = fidx[j2];
        float wgt = fw[j2];
        const float4* xr = (const float4*)(x + ((size_t)b * N + idx) * INPUT_DIM);
        float4 v = xr[tid];
        acc.x = fmaf(wgt, v.x, acc.x);
        acc.y = fmaf(wgt, v.y, acc.y);
        acc.z = fmaf(wgt, v.z, acc.z);
        acc.w = fmaf(wgt, v.w, acc.w);
    }
    ((float4*)(Z + (size_t)b * INPUT_DIM))[tid] = acc;
}

extern "C" void kernel_launch(void* const* d_in, const int* in_sizes, int n_in,
                              void* d_out, int out_size, void* d_ws, size_t ws_size,
                              hipStream_t stream)
{
    const float* x  = (const float*)d_in[0];
    const float* Wv = (const float*)d_in[1];
    const float* bv = (const float*)d_in[2];
    const float* Wu = (const float*)d_in[3];
    const float* bu = (const float*)d_in[4];
    const float* Ww = (const float*)d_in[5];
    const float* bw = (const float*)d_in[6];

    const int B = 8;
    const int N = in_sizes[0] / (B * INPUT_DIM);   // 50000

    float* Z = (float*)d_out;                              // [B,1024]
    float* atten = (float*)d_out + (size_t)B * INPUT_DIM;  // [B,N]

    // workspace layout
    char* p = (char*)d_ws;
    float* scores = (float*)p;                  p += (size_t)B * N * sizeof(float);
    unsigned short* wp_hi = (unsigned short*)p; p += (size_t)INPUT_DIM * 256 * sizeof(unsigned short);
    float* cand_v = (float*)p;                  p += (size_t)B * NSEL1 * 2 * KC * sizeof(float);
    int* cand_i = (int*)p;                      p += (size_t)B * NSEL1 * 2 * KC * sizeof(int);
    int* cand_idx = (int*)p;                    p += (size_t)B * 2 * KC * sizeof(int);
    float* cand_score = (float*)p;

    repack_kernel<<<512, 64, 0, stream>>>(Wv, Wu, wp_hi);

    dim3 g1((N + BM - 1) / BM, B);
    scores_kernel<<<g1, STH, 0, stream>>>(x, wp_hi, bv, bu, Ww, bw, scores, atten, N);

    int CH = (N + NSEL1 - 1) / NSEL1;
    dim3 g2(NSEL1, B);
    select1_kernel<<<g2, 64, 0, stream>>>(scores, cand_v, cand_i, N, CH);
    select2_kernel<<<B, 64, 0, stream>>>(cand_v, cand_i, cand_idx);

    dim3 g3(2 * KC, B);
    rescore_kernel<<<g3, 256, 0, stream>>>(x, Wv, bv, Wu, bu, Ww, bw, cand_idx, cand_score, N);
    final_kernel<<<B, 256, 0, stream>>>(x, cand_idx, cand_score, atten, Z, N);
}

// Round 12
// 658.434 us; speedup vs baseline: 1.2738x; 1.1586x over previous
//
#include <hip/hip_runtime.h>
#include <math.h>
#include <float.h>

#define INPUT_DIM 1024
#define HIDDEN 128
#define KSEL 10
#define KC 12                 // candidates per side (containment margin 2)

// scores kernel geometry: 8 waves (512 thr), block tile 64 rows x 256 pc.
// wave tile: 64 rows x 32 pc (4m x 2n fragments of 16x16), single-term bf16.
#define BM 64
#define BK 64
#define KT (INPUT_DIM / BK)   // 16
#define STH 512
#define NSEL1 32              // stage-1 chunks per bag

typedef short short8 __attribute__((ext_vector_type(8)));
typedef float f32x4 __attribute__((ext_vector_type(4)));

static __device__ __forceinline__ unsigned short f2bf(float f) {
    union { float f; unsigned u; } v; v.f = f;
    unsigned r = v.u + 0x7FFF + ((v.u >> 16) & 1);   // RNE
    return (unsigned short)(r >> 16);
}
static __device__ __forceinline__ float fast_tanh(float a) {
    float e = __expf(2.0f * a);
    return 1.0f - 2.0f / (e + 1.0f);
}
static __device__ __forceinline__ float fast_sigmoid(float a) {
    return 1.0f / (1.0f + __expf(-a));
}

// ---------------------------------------------------------------------------
// Repack W into MFMA B-fragment order (16x16x32), bf16 RNE. Approx error is
// absorbed by the exact fp32 rescore of the top/bottom-12 candidates.
// pc = 2h + (0 Wv, 1 Wu). wp[kg][cg][lane][e]: k = kg*32+(lane>>4)*8+e,
// pc = cg*16+(lane&15). grid 512 (= 32 kg x 16 cg) x 64.
// ---------------------------------------------------------------------------
__global__ __launch_bounds__(64) void repack_kernel(
    const float* __restrict__ Wv, const float* __restrict__ Wu,
    unsigned short* __restrict__ wp_hi)
{
    int bid = blockIdx.x;           // kg*16 + cg
    int l = threadIdx.x;
    int pc = (bid & 15) * 16 + (l & 15);
    int h = pc >> 1;
    const float* src = (pc & 1) ? Wu : Wv;
    int kbase = (bid >> 4) * 32 + (l >> 4) * 8;
    size_t off = ((size_t)bid * 64 + l) * 8;
    #pragma unroll
    for (int e = 0; e < 8; ++e)
        wp_hi[off + e] = f2bf(src[(size_t)(kbase + e) * HIDDEN + h]);
}

// ---------------------------------------------------------------------------
// Kernel 1: approx scores, SINGLE bf16 MFMA term (x_bf16 (dot) w_bf16).
// x converted fp32->bf16 ONCE at stage time (register staging: 2 float4
// loads -> 4 cvt_pk -> 1 ds_write_b128 per lane per tile). LDS holds bf16:
// half the LDS bytes and half the ds_reads of the fp32 scheme; no split
// VALU in the MFMA phase. 4-buffer LDS rotation, unroll-4 (static indices),
// 2 x-tiles + 2 B-sets in registers, one lgkm-only barrier per K-step.
// XOR swizzle: LDS[row][c] = x[row][c ^ (row&7)] (8-elem chunks).
// HBM x-read (260 us) is the design floor; all other pipes ~120 us.
// ---------------------------------------------------------------------------
__global__ __launch_bounds__(STH) void scores_kernel(
    const float* __restrict__ x, const unsigned short* __restrict__ wp,
    const float* __restrict__ bv, const float* __restrict__ bu,
    const float* __restrict__ Ww, const float* __restrict__ bw,
    float* __restrict__ scores, float* __restrict__ atten, int N)
{
    __shared__ __align__(16) unsigned short xs[4][BM * BK];  // 4 x 8 KB bf16
    __shared__ float partial[8][BM];                         // 2 KB

    const int tid = threadIdx.x;
    const int l = tid & 63;
    const int w = tid >> 6;        // wave 0..7: pc slab [w*32, w*32+32)
    const int b = blockIdx.y;
    const int i0 = blockIdx.x * BM;
    const float* xb = x + (size_t)b * N * INPUT_DIM;

    // staging: wave w stages rows [w*8, w*8+8); lane -> row w*8+(l>>3),
    // global chunk (l&7) (8 floats), LDS chunk (l&7)^(l>>3)  [row&7 == l>>3]
    const float* gpx = xb + (size_t)min(i0 + w * 8 + (l >> 3), N - 1) * INPUT_DIM
                          + (l & 7) * 8;
    const int xwidx = (w * 8 + (l >> 3)) * BK + (((l & 7) ^ (l >> 3)) * 8);

    f32x4 acc[4][2];
    #pragma unroll
    for (int m = 0; m < 4; ++m)
        #pragma unroll
        for (int n = 0; n < 2; ++n)
            acc[m][n] = (f32x4){0.f, 0.f, 0.f, 0.f};

#define XLOAD(XA, XB, T) do { \
        const float* _p = gpx + (size_t)min((T), KT - 1) * BK; \
        XA = *(const float4*)_p; \
        XB = *(const float4*)(_p + 4); \
    } while (0)

#define XWRITE(XA, XB, SLOT) do { \
        unsigned p0, p1, p2, p3; \
        asm("v_cvt_pk_bf16_f32 %0, %1, %2" : "=v"(p0) : "v"(XA.x), "v"(XA.y)); \
        asm("v_cvt_pk_bf16_f32 %0, %1, %2" : "=v"(p1) : "v"(XA.z), "v"(XA.w)); \
        asm("v_cvt_pk_bf16_f32 %0, %1, %2" : "=v"(p2) : "v"(XB.x), "v"(XB.y)); \
        asm("v_cvt_pk_bf16_f32 %0, %1, %2" : "=v"(p3) : "v"(XB.z), "v"(XB.w)); \
        *(uint4*)(&xs[(SLOT)][xwidx]) = make_uint4(p0, p1, p2, p3); \
    } while (0)

#define BLOAD(BH, KT_) do { \
        int _ktc = min((KT_), KT - 1); \
        _Pragma("unroll") \
        for (int ks = 0; ks < 2; ++ks) \
            _Pragma("unroll") \
            for (int n = 0; n < 2; ++n) { \
                unsigned boff = (unsigned)(((((_ktc) * 2 + ks) * 16 + w * 2 + n) * 64 + l) * 8); \
                BH[ks][n] = *(const short8*)(wp + boff); \
            } \
    } while (0)

#define MFMA_KT(SLOT, BH) do { \
        __builtin_amdgcn_s_setprio(1); \
        _Pragma("unroll") \
        for (int ks = 0; ks < 2; ++ks) \
            _Pragma("unroll") \
            for (int m = 0; m < 4; ++m) { \
                int rowt = m * 16 + (l & 15); \
                int chunk = (ks * 4 + (l >> 4)) ^ (l & 7); \
                short8 a = *(const short8*)(&xs[(SLOT)][rowt * BK + chunk * 8]); \
                _Pragma("unroll") \
                for (int n = 0; n < 2; ++n) \
                    acc[m][n] = __builtin_amdgcn_mfma_f32_16x16x32_bf16(a, BH[ks][n], acc[m][n], 0, 0, 0); \
            } \
        __builtin_amdgcn_s_setprio(0); \
    } while (0)

#define LGKM_BARRIER() do { \
        asm volatile("s_waitcnt lgkmcnt(0)" ::: "memory"); \
        __builtin_amdgcn_s_barrier(); \
    } while (0)

    float4 xA0, xA1, xB0, xB1;
    short8 bhA[2][2], bhB[2][2];

    // prologue: tile0 staged; x(1)->A, x(2)->B, B(0)->A, B(1)->B in flight
    XLOAD(xA0, xA1, 0);
    BLOAD(bhA, 0);
    XWRITE(xA0, xA1, 0);               // compiler inserts vmcnt wait for xA
    XLOAD(xA0, xA1, 1);
    XLOAD(xB0, xB1, 2);
    BLOAD(bhB, 1);
    LGKM_BARRIER();

    for (int j = 0; j < KT / 4; ++j) {
        #pragma unroll
        for (int i = 0; i < 4; ++i) {
            const int kt = j * 4 + i;          // i static -> slots static
            if ((i & 1) == 0) {
                MFMA_KT(i, bhA);               // tile kt, B(kt)
                __builtin_amdgcn_sched_barrier(0);
                XWRITE(xA0, xA1, (i + 1) & 3); // tile kt+1 (loaded kt-2)
                BLOAD(bhA, kt + 2);
                XLOAD(xA0, xA1, kt + 3);
                __builtin_amdgcn_sched_barrier(0);
                LGKM_BARRIER();
            } else {
                MFMA_KT(i, bhB);
                __builtin_amdgcn_sched_barrier(0);
                XWRITE(xB0, xB1, (i + 1) & 3);
                BLOAD(bhB, kt + 2);
                XLOAD(xB0, xB1, kt + 3);
                __builtin_amdgcn_sched_barrier(0);
                LGKM_BARRIER();
            }
        }
    }

#undef XLOAD
#undef XWRITE
#undef BLOAD
#undef MFMA_KT
#undef LGKM_BARRIER

    // ---- epilogue: gate, project, row-reduce ----
    float bvv[2], buu[2], www[2];
    #pragma unroll
    for (int n = 0; n < 2; ++n) {
        int h = (w * 32 + n * 16 + (l & 15)) >> 1;
        bvv[n] = bv[h]; buu[n] = bu[h]; www[n] = Ww[h];
    }
    const bool isV = ((l & 1) == 0);

    #pragma unroll
    for (int m = 0; m < 4; ++m) {
        float cs[4] = {0.f, 0.f, 0.f, 0.f};
        #pragma unroll
        for (int n = 0; n < 2; ++n) {
            #pragma unroll
            for (int r = 0; r < 4; ++r) {
                float v = acc[m][n][r];
                float u = __shfl_xor(v, 1, 64);     // partner col (U pre-act)
                if (isV)
                    cs[r] += fast_tanh(v + bvv[n]) * fast_sigmoid(u + buu[n]) * www[n];
            }
        }
        #pragma unroll
        for (int r = 0; r < 4; ++r) {
            #pragma unroll
            for (int off = 1; off < 16; off <<= 1)
                cs[r] += __shfl_xor(cs[r], off, 64);
        }
        if ((l & 15) == 0) {
            #pragma unroll
            for (int r = 0; r < 4; ++r)
                partial[w][m * 16 + (l >> 4) * 4 + r] = cs[r];
        }
    }
    __syncthreads();

    if (tid < BM) {
        int gi2 = i0 + tid;
        if (gi2 < N) {
            float s = bw[0];
            #pragma unroll
            for (int ww2 = 0; ww2 < 8; ++ww2) s += partial[ww2][tid];
            scores[(size_t)b * N + gi2] = s;
            atten[(size_t)b * N + gi2] = 0.0f;
        }
    }
}

// ---------------------------------------------------------------------------
// Kernel 2a: per (chunk, bag) approx top-12 / bottom-12. 1 wave per block.
// ---------------------------------------------------------------------------
__global__ __launch_bounds__(64) void select1_kernel(
    const float* __restrict__ scores, float* __restrict__ cv, int* __restrict__ ci,
    int N, int CH)
{
    const int r = blockIdx.x, b = blockIdx.y;
    const int tid = threadIdx.x;
    const float* s = scores + (size_t)b * N;
    const int start = r * CH;
    const int end = min(N, start + CH);

    float tv[KC]; int ti[KC];
    float lv[KC]; int li[KC];
    #pragma unroll
    for (int j = 0; j < KC; ++j) { tv[j] = -FLT_MAX; ti[j] = -1; lv[j] = FLT_MAX; li[j] = -1; }

    for (int i = start + tid; i < end; i += 64) {
        float v = s[i];
        if (v > tv[KC-1]) {
            #pragma unroll
            for (int j = KC-1; j >= 1; --j) {
                if (v > tv[j-1])      { tv[j] = tv[j-1]; ti[j] = ti[j-1]; }
                else if (v > tv[j])   { tv[j] = v;       ti[j] = i;       }
            }
            if (v > tv[0]) { tv[0] = v; ti[0] = i; }
        }
        if (v < lv[KC-1]) {
            #pragma unroll
            for (int j = KC-1; j >= 1; --j) {
                if (v < lv[j-1])      { lv[j] = lv[j-1]; li[j] = li[j-1]; }
                else if (v < lv[j])   { lv[j] = v;       li[j] = i;       }
            }
            if (v < lv[0]) { lv[0] = v; li[0] = i; }
        }
    }

    size_t base = ((size_t)b * NSEL1 + r) * 2 * KC;
    for (int rd = 0; rd < KC; ++rd) {
        float v = tv[0]; int who = tid;
        #pragma unroll
        for (int off = 32; off > 0; off >>= 1) {
            float ov = __shfl_down(v, off, 64);
            int ow = __shfl_down(who, off, 64);
            if (ov > v) { v = ov; who = ow; }
        }
        int bwho = __shfl(who, 0, 64);
        if (tid == bwho) {
            cv[base + rd] = tv[0]; ci[base + rd] = ti[0];
            #pragma unroll
            for (int j = 0; j < KC-1; ++j) { tv[j] = tv[j+1]; ti[j] = ti[j+1]; }
            tv[KC-1] = -FLT_MAX;
        }
    }
    for (int rd = 0; rd < KC; ++rd) {
        float v = lv[0]; int who = tid;
        #pragma unroll
        for (int off = 32; off > 0; off >>= 1) {
            float ov = __shfl_down(v, off, 64);
            int ow = __shfl_down(who, off, 64);
            if (ov < v) { v = ov; who = ow; }
        }
        int bwho = __shfl(who, 0, 64);
        if (tid == bwho) {
            cv[base + KC + rd] = lv[0]; ci[base + KC + rd] = li[0];
            #pragma unroll
            for (int j = 0; j < KC-1; ++j) { lv[j] = lv[j+1]; li[j] = li[j+1]; }
            lv[KC-1] = FLT_MAX;
        }
    }
}

// ---------------------------------------------------------------------------
// Kernel 2b: per bag, merge -> global approx top-12/bottom-12 indices.
// ---------------------------------------------------------------------------
__global__ __launch_bounds__(64) void select2_kernel(
    const float* __restrict__ cv, const int* __restrict__ ci,
    int* __restrict__ cand_idx)
{
    const int b = blockIdx.x;
    const int tid = threadIdx.x;

    float tv[KC]; int ti[KC];
    float lv[KC]; int li[KC];
    #pragma unroll
    for (int j = 0; j < KC; ++j) { tv[j] = -FLT_MAX; ti[j] = -1; lv[j] = FLT_MAX; li[j] = -1; }

    for (int c = tid; c < NSEL1 * KC; c += 64) {
        int rr = c / KC, jj = c % KC;
        size_t base = ((size_t)b * NSEL1 + rr) * 2 * KC;
        {
            float v = cv[base + jj]; int idx = ci[base + jj];
            if (v > tv[KC-1]) {
                #pragma unroll
                for (int j = KC-1; j >= 1; --j) {
                    if (v > tv[j-1])      { tv[j] = tv[j-1]; ti[j] = ti[j-1]; }
                    else if (v > tv[j])   { tv[j] = v;       ti[j] = idx;     }
                }
                if (v > tv[0]) { tv[0] = v; ti[0] = idx; }
            }
        }
        {
            float v = cv[base + KC + jj]; int idx = ci[base + KC + jj];
            if (v < lv[KC-1]) {
                #pragma unroll
                for (int j = KC-1; j >= 1; --j) {
                    if (v < lv[j-1])      { lv[j] = lv[j-1]; li[j] = li[j-1]; }
                    else if (v < lv[j])   { lv[j] = v;       li[j] = idx;     }
                }
                if (v < lv[0]) { lv[0] = v; li[0] = idx; }
            }
        }
    }

    for (int rd = 0; rd < KC; ++rd) {
        float v = tv[0]; int who = tid;
        #pragma unroll
        for (int off = 32; off > 0; off >>= 1) {
            float ov = __shfl_down(v, off, 64);
            int ow = __shfl_down(who, off, 64);
            if (ov > v) { v = ov; who = ow; }
        }
        int bwho = __shfl(who, 0, 64);
        if (tid == bwho) {
            cand_idx[b * 2 * KC + rd] = ti[0];
            #pragma unroll
            for (int j = 0; j < KC-1; ++j) { tv[j] = tv[j+1]; ti[j] = ti[j+1]; }
            tv[KC-1] = -FLT_MAX;
        }
    }
    for (int rd = 0; rd < KC; ++rd) {
        float v = lv[0]; int who = tid;
        #pragma unroll
        for (int off = 32; off > 0; off >>= 1) {
            float ov = __shfl_down(v, off, 64);
            int ow = __shfl_down(who, off, 64);
            if (ov < v) { v = ov; who = ow; }
        }
        int bwho = __shfl(who, 0, 64);
        if (tid == bwho) {
            cand_idx[b * 2 * KC + KC + rd] = li[0];
            #pragma unroll
            for (int j = 0; j < KC-1; ++j) { lv[j] = lv[j+1]; li[j] = li[j+1]; }
            lv[KC-1] = FLT_MAX;
        }
    }
}

// ---------------------------------------------------------------------------
// Kernel 3: exact fp32 rescore of each candidate row.
// ---------------------------------------------------------------------------
__global__ __launch_bounds__(256) void rescore_kernel(
    const float* __restrict__ x,
    const float* __restrict__ Wv, const float* __restrict__ bv,
    const float* __restrict__ Wu, const float* __restrict__ bu,
    const float* __restrict__ Ww, const float* __restrict__ bw,
    const int* __restrict__ cand_idx, float* __restrict__ cand_score, int N)
{
    const int j = blockIdx.x, b = blockIdx.y;
    const int tid = threadIdx.x;
    __shared__ float xsr[INPUT_DIM];
    __shared__ float sp[4];

    int idx = cand_idx[b * 2 * KC + j];
    const float* xr = x + ((size_t)b * N + idx) * INPUT_DIM;
    *(float4*)(&xsr[tid * 4]) = *(const float4*)(&xr[tid * 4]);
    __syncthreads();

    const int h = tid >> 1;
    const int isU = tid & 1;
    const float* W = isU ? Wu : Wv;
    float s = 0.f;
    #pragma unroll 8
    for (int k = 0; k < INPUT_DIM; ++k)
        s = fmaf(xsr[k], W[(size_t)k * HIDDEN + h], s);

    float other = __shfl_xor(s, 1, 64);
    float g = 0.f;
    if (!isU) {
        float vv = tanhf(s + bv[h]);
        float uu = 1.0f / (1.0f + expf(-(other + bu[h])));
        g = vv * uu * Ww[h];
    }
    #pragma unroll
    for (int off = 1; off < 64; off <<= 1) g += __shfl_xor(g, off, 64);
    if ((tid & 63) == 0) sp[tid >> 6] = g;
    __syncthreads();
    if (tid == 0)
        cand_score[b * 2 * KC + j] = sp[0] + sp[1] + sp[2] + sp[3] + bw[0];
}

// ---------------------------------------------------------------------------
// Kernel 4: exact top/bottom-10 sets, exact softmax, scatter atten, gather Z.
// ---------------------------------------------------------------------------
__global__ __launch_bounds__(256) void final_kernel(
    const float* __restrict__ x, const int* __restrict__ cand_idx,
    const float* __restrict__ cand_score,
    float* __restrict__ atten, float* __restrict__ Z, int N)
{
    const int b = blockIdx.x;
    const int tid = threadIdx.x;
    __shared__ int fidx[2 * KSEL];
    __shared__ float fw[2 * KSEL];

    if (tid == 0) {
        float cs[2 * KC]; int ciX[2 * KC]; bool used[2 * KC];
        #pragma unroll
        for (int j2 = 0; j2 < 2 * KC; ++j2) {
            cs[j2] = cand_score[b * 2 * KC + j2];
            ciX[j2] = cand_idx[b * 2 * KC + j2];
            used[j2] = false;
        }
        float fs[2 * KSEL];
        for (int r = 0; r < KSEL; ++r) {
            int best = -1; float bvv = -FLT_MAX;
            for (int j2 = 0; j2 < KC; ++j2)
                if (!used[j2] && cs[j2] > bvv) { bvv = cs[j2]; best = j2; }
            used[best] = true; fidx[r] = ciX[best]; fs[r] = bvv;
        }
        for (int r = 0; r < KSEL; ++r) {
            int best = -1; float bvv = FLT_MAX;
            for (int j2 = KC; j2 < 2 * KC; ++j2)
                if (!used[j2] && cs[j2] < bvv) { bvv = cs[j2]; best = j2; }
            used[best] = true; fidx[KSEL + r] = ciX[best]; fs[KSEL + r] = bvv;
        }
        float m = -FLT_MAX;
        for (int j2 = 0; j2 < 2 * KSEL; ++j2) m = fmaxf(m, fs[j2]);
        float e[2 * KSEL], sum = 0.f;
        for (int j2 = 0; j2 < 2 * KSEL; ++j2) { e[j2] = expf(fs[j2] - m); sum += e[j2]; }
        float inv = 1.0f / sum;
        for (int j2 = 0; j2 < 2 * KSEL; ++j2) {
            fw[j2] = e[j2] * inv;
            atten[(size_t)b * N + fidx[j2]] = fw[j2];
        }
    }
    __syncthreads();

    float4 acc = make_float4(0.f, 0.f, 0.f, 0.f);
    #pragma unroll
    for (int j2 = 0; j2 < 2 * KSEL; ++j2) {
        int idx = fidx[j2];
        float wgt = fw[j2];
        const float4* xr = (const float4*)(x + ((size_t)b * N + idx) * INPUT_DIM);
        float4 v = xr[tid];
        acc.x = fmaf(wgt, v.x, acc.x);
        acc.y = fmaf(wgt, v.y, acc.y);
        acc.z = fmaf(wgt, v.z, acc.z);
        acc.w = fmaf(wgt, v.w, acc.w);
    }
    ((float4*)(Z + (size_t)b * INPUT_DIM))[tid] = acc;
}

extern "C" void kernel_launch(void* const* d_in, const int* in_sizes, int n_in,
                              void* d_out, int out_size, void* d_ws, size_t ws_size,
                              hipStream_t stream)
{
    const float* x  = (const float*)d_in[0];
    const float* Wv = (const float*)d_in[1];
    const float* bv = (const float*)d_in[2];
    const float* Wu = (const float*)d_in[3];
    const float* bu = (const float*)d_in[4];
    const float* Ww = (const float*)d_in[5];
    const float* bw = (const float*)d_in[6];

    const int B = 8;
    const int N = in_sizes[0] / (B * INPUT_DIM);   // 50000

    float* Z = (float*)d_out;                              // [B,1024]
    float* atten = (float*)d_out + (size_t)B * INPUT_DIM;  // [B,N]

    // workspace layout
    char* p = (char*)d_ws;
    float* scores = (float*)p;                  p += (size_t)B * N * sizeof(float);
    unsigned short* wp = (unsigned short*)p;    p += (size_t)INPUT_DIM * 256 * sizeof(unsigned short);
    float* cand_v = (float*)p;                  p += (size_t)B * NSEL1 * 2 * KC * sizeof(float);
    int* cand_i = (int*)p;                      p += (size_t)B * NSEL1 * 2 * KC * sizeof(int);
    int* cand_idx = (int*)p;                    p += (size_t)B * 2 * KC * sizeof(int);
    float* cand_score = (float*)p;

    repack_kernel<<<512, 64, 0, stream>>>(Wv, Wu, wp);

    dim3 g1((N + BM - 1) / BM, B);
    scores_kernel<<<g1, STH, 0, stream>>>(x, wp, bv, bu, Ww, bw, scores, atten, N);

    int CH = (N + NSEL1 - 1) / NSEL1;
    dim3 g2(NSEL1, B);
    select1_kernel<<<g2, 64, 0, stream>>>(scores, cand_v, cand_i, N, CH);
    select2_kernel<<<B, 64, 0, stream>>>(cand_v, cand_i, cand_idx);

    dim3 g3(2 * KC, B);
    rescore_kernel<<<g3, 256, 0, stream>>>(x, Wv, bv, Wu, bu, Ww, bw, cand_idx, cand_score, N);
    final_kernel<<<B, 256, 0, stream>>>(x, cand_idx, cand_score, atten, Z, N);
}

// Round 13
// 549.604 us; speedup vs baseline: 1.5260x; 1.1980x over previous
//
#include <hip/hip_runtime.h>
#include <math.h>
#include <float.h>

#define INPUT_DIM 1024
#define HIDDEN 128
#define KSEL 10
#define KC 12                 // candidates per side (containment margin 2)

// scores kernel geometry: 4 waves (256 thr), block tile 64 rows x 256 pc.
// wave tile: 64 rows x 64 pc (4m x 4n fragments of 16x16), single-term bf16.
// 3 independent blocks/CU is the design goal (VGPR ~150, LDS 33 KB).
#define BM 64
#define BK 64
#define KT (INPUT_DIM / BK)   // 16
#define STH 256
#define NSEL1 32              // stage-1 chunks per bag

typedef short short8 __attribute__((ext_vector_type(8)));
typedef float f32x4 __attribute__((ext_vector_type(4)));

static __device__ __forceinline__ unsigned short f2bf(float f) {
    union { float f; unsigned u; } v; v.f = f;
    unsigned r = v.u + 0x7FFF + ((v.u >> 16) & 1);   // RNE
    return (unsigned short)(r >> 16);
}
static __device__ __forceinline__ float fast_tanh(float a) {
    float e = __expf(2.0f * a);
    return 1.0f - 2.0f / (e + 1.0f);
}
static __device__ __forceinline__ float fast_sigmoid(float a) {
    return 1.0f / (1.0f + __expf(-a));
}

// ---------------------------------------------------------------------------
// Repack W into MFMA B-fragment order (16x16x32), bf16 RNE. Approx error is
// absorbed by the exact fp32 rescore of the top/bottom-12 candidates.
// pc = 2h + (0 Wv, 1 Wu). wp[kg][cg][lane][e]: k = kg*32+(lane>>4)*8+e,
// pc = cg*16+(lane&15). grid 512 (= 32 kg x 16 cg) x 64.
// ---------------------------------------------------------------------------
__global__ __launch_bounds__(64) void repack_kernel(
    const float* __restrict__ Wv, const float* __restrict__ Wu,
    unsigned short* __restrict__ wp_hi)
{
    int bid = blockIdx.x;           // kg*16 + cg
    int l = threadIdx.x;
    int pc = (bid & 15) * 16 + (l & 15);
    int h = pc >> 1;
    const float* src = (pc & 1) ? Wu : Wv;
    int kbase = (bid >> 4) * 32 + (l >> 4) * 8;
    size_t off = ((size_t)bid * 64 + l) * 8;
    #pragma unroll
    for (int e = 0; e < 8; ++e)
        wp_hi[off + e] = f2bf(src[(size_t)(kbase + e) * HIDDEN + h]);
}

// ---------------------------------------------------------------------------
// Kernel 1: approx scores, SINGLE bf16 MFMA term (x_bf16 (dot) w_bf16).
// 4 waves, wave tile 64 rows x 64 pc (cg = w*4..w*4+3). x converted
// fp32->bf16 once at stage time (reg staging), bf16 LDS, 4-slot rotation,
// XOR swizzle, one lgkm-only barrier per K-step. x prefetch 2 tiles deep
// (flight ~2 periods >> HBM latency); B loaded per-kt (L2, ~300 cy, covered
// by 3 waves/SIMD). Small blocks -> 3 INDEPENDENT blocks/CU so barrier
// stalls of one block overlap streaming of the others.
// ---------------------------------------------------------------------------
__global__ __launch_bounds__(STH) void scores_kernel(
    const float* __restrict__ x, const unsigned short* __restrict__ wp,
    const float* __restrict__ bv, const float* __restrict__ bu,
    const float* __restrict__ Ww, const float* __restrict__ bw,
    float* __restrict__ scores, float* __restrict__ atten, int N)
{
    __shared__ __align__(16) unsigned short xs[4][BM * BK];  // 4 x 8 KB bf16
    __shared__ float partial[4][BM];                         // 1 KB

    const int tid = threadIdx.x;
    const int l = tid & 63;
    const int w = tid >> 6;        // wave 0..3: pc slab [w*64, w*64+64)
    const int b = blockIdx.y;
    const int i0 = blockIdx.x * BM;
    const float* xb = x + (size_t)b * N * INPUT_DIM;

    // staging: wave w stages rows [w*16, w*16+16); per lane two rows:
    // row_r = w*16 + r*8 + (l>>3), fp32 chunk (l&7) (8 floats = 32 B).
    // LDS bf16 chunk = (l&7) ^ (l>>3)   [row&7 == l>>3 for both r]
    const float* gp0 = xb + (size_t)min(i0 + w * 16 + (l >> 3), N - 1) * INPUT_DIM + (l & 7) * 8;
    const float* gp1 = xb + (size_t)min(i0 + w * 16 + 8 + (l >> 3), N - 1) * INPUT_DIM + (l & 7) * 8;
    const int xw0 = (w * 16 + (l >> 3)) * BK + (((l & 7) ^ (l >> 3)) * 8);
    const int xw1 = (w * 16 + 8 + (l >> 3)) * BK + (((l & 7) ^ (l >> 3)) * 8);

    f32x4 acc[4][4];
    #pragma unroll
    for (int m = 0; m < 4; ++m)
        #pragma unroll
        for (int n = 0; n < 4; ++n)
            acc[m][n] = (f32x4){0.f, 0.f, 0.f, 0.f};

#define XLOAD(X0, X1, X2, X3, T) do { \
        const size_t _o = (size_t)min((T), KT - 1) * BK; \
        X0 = *(const float4*)(gp0 + _o); \
        X1 = *(const float4*)(gp0 + _o + 4); \
        X2 = *(const float4*)(gp1 + _o); \
        X3 = *(const float4*)(gp1 + _o + 4); \
    } while (0)

#define XWRITE(X0, X1, X2, X3, SLOT) do { \
        unsigned p0, p1, p2, p3, q0, q1, q2, q3; \
        asm("v_cvt_pk_bf16_f32 %0, %1, %2" : "=v"(p0) : "v"(X0.x), "v"(X0.y)); \
        asm("v_cvt_pk_bf16_f32 %0, %1, %2" : "=v"(p1) : "v"(X0.z), "v"(X0.w)); \
        asm("v_cvt_pk_bf16_f32 %0, %1, %2" : "=v"(p2) : "v"(X1.x), "v"(X1.y)); \
        asm("v_cvt_pk_bf16_f32 %0, %1, %2" : "=v"(p3) : "v"(X1.z), "v"(X1.w)); \
        asm("v_cvt_pk_bf16_f32 %0, %1, %2" : "=v"(q0) : "v"(X2.x), "v"(X2.y)); \
        asm("v_cvt_pk_bf16_f32 %0, %1, %2" : "=v"(q1) : "v"(X2.z), "v"(X2.w)); \
        asm("v_cvt_pk_bf16_f32 %0, %1, %2" : "=v"(q2) : "v"(X3.x), "v"(X3.y)); \
        asm("v_cvt_pk_bf16_f32 %0, %1, %2" : "=v"(q3) : "v"(X3.z), "v"(X3.w)); \
        *(uint4*)(&xs[(SLOT)][xw0]) = make_uint4(p0, p1, p2, p3); \
        *(uint4*)(&xs[(SLOT)][xw1]) = make_uint4(q0, q1, q2, q3); \
    } while (0)

#define BLOAD(KT_) do { \
        _Pragma("unroll") \
        for (int ks = 0; ks < 2; ++ks) \
            _Pragma("unroll") \
            for (int n = 0; n < 4; ++n) { \
                unsigned boff = (unsigned)(((((KT_) * 2 + ks) * 16 + w * 4 + n) * 64 + l) * 8); \
                bh[ks][n] = *(const short8*)(wp + boff); \
            } \
    } while (0)

#define MFMA_KT(SLOT) do { \
        __builtin_amdgcn_s_setprio(1); \
        _Pragma("unroll") \
        for (int ks = 0; ks < 2; ++ks) \
            _Pragma("unroll") \
            for (int m = 0; m < 4; ++m) { \
                int rowt = m * 16 + (l & 15); \
                int chunk = (ks * 4 + (l >> 4)) ^ (l & 7); \
                short8 a = *(const short8*)(&xs[(SLOT)][rowt * BK + chunk * 8]); \
                _Pragma("unroll") \
                for (int n = 0; n < 4; ++n) \
                    acc[m][n] = __builtin_amdgcn_mfma_f32_16x16x32_bf16(a, bh[ks][n], acc[m][n], 0, 0, 0); \
            } \
        __builtin_amdgcn_s_setprio(0); \
    } while (0)

#define LGKM_BARRIER() do { \
        asm volatile("s_waitcnt lgkmcnt(0)" ::: "memory"); \
        __builtin_amdgcn_s_barrier(); \
    } while (0)

    short8 bh[2][4];                       // single B set (32 VGPR)
    float4 a0, a1, a2, a3, c0, c1, c2, c3; // two x tiles in flight (32 VGPR)

    // prologue: stage tile0; tiles 1 and 2 in flight
    XLOAD(a0, a1, a2, a3, 0);
    XWRITE(a0, a1, a2, a3, 0);             // one-time vmcnt stall for tile0
    XLOAD(a0, a1, a2, a3, 1);
    XLOAD(c0, c1, c2, c3, 2);
    LGKM_BARRIER();

    for (int j = 0; j < KT / 4; ++j) {
        #pragma unroll
        for (int ii = 0; ii < 4; ++ii) {
            const int kt = j * 4 + ii;     // slot = kt & 3 == ii (static)
            BLOAD(kt);
            MFMA_KT(ii);
            __builtin_amdgcn_sched_barrier(0);
            if ((ii & 1) == 0) {
                XWRITE(a0, a1, a2, a3, (ii + 1) & 3);   // tile kt+1
                XLOAD(a0, a1, a2, a3, kt + 3);          // 2-period flight
            } else {
                XWRITE(c0, c1, c2, c3, (ii + 1) & 3);
                XLOAD(c0, c1, c2, c3, kt + 3);
            }
            __builtin_amdgcn_sched_barrier(0);
            LGKM_BARRIER();
        }
    }

#undef XLOAD
#undef XWRITE
#undef BLOAD
#undef MFMA_KT
#undef LGKM_BARRIER

    // ---- epilogue: gate, project, row-reduce ----
    float bvv[4], buu[4], www[4];
    #pragma unroll
    for (int n = 0; n < 4; ++n) {
        int h = (w * 64 + n * 16 + (l & 15)) >> 1;
        bvv[n] = bv[h]; buu[n] = bu[h]; www[n] = Ww[h];
    }
    const bool isV = ((l & 1) == 0);

    #pragma unroll
    for (int m = 0; m < 4; ++m) {
        float cs[4] = {0.f, 0.f, 0.f, 0.f};
        #pragma unroll
        for (int n = 0; n < 4; ++n) {
            #pragma unroll
            for (int r = 0; r < 4; ++r) {
                float v = acc[m][n][r];
                float u = __shfl_xor(v, 1, 64);     // partner col (U pre-act)
                if (isV)
                    cs[r] += fast_tanh(v + bvv[n]) * fast_sigmoid(u + buu[n]) * www[n];
            }
        }
        #pragma unroll
        for (int r = 0; r < 4; ++r) {
            #pragma unroll
            for (int off = 1; off < 16; off <<= 1)
                cs[r] += __shfl_xor(cs[r], off, 64);
        }
        if ((l & 15) == 0) {
            #pragma unroll
            for (int r = 0; r < 4; ++r)
                partial[w][m * 16 + (l >> 4) * 4 + r] = cs[r];
        }
    }
    __syncthreads();

    if (tid < BM) {
        int gi2 = i0 + tid;
        if (gi2 < N) {
            float s = bw[0] + partial[0][tid] + partial[1][tid]
                            + partial[2][tid] + partial[3][tid];
            scores[(size_t)b * N + gi2] = s;
            atten[(size_t)b * N + gi2] = 0.0f;
        }
    }
}

// ---------------------------------------------------------------------------
// Kernel 2a: per (chunk, bag) approx top-12 / bottom-12. 1 wave per block.
// ---------------------------------------------------------------------------
__global__ __launch_bounds__(64) void select1_kernel(
    const float* __restrict__ scores, float* __restrict__ cv, int* __restrict__ ci,
    int N, int CH)
{
    const int r = blockIdx.x, b = blockIdx.y;
    const int tid = threadIdx.x;
    const float* s = scores + (size_t)b * N;
    const int start = r * CH;
    const int end = min(N, start + CH);

    float tv[KC]; int ti[KC];
    float lv[KC]; int li[KC];
    #pragma unroll
    for (int j = 0; j < KC; ++j) { tv[j] = -FLT_MAX; ti[j] = -1; lv[j] = FLT_MAX; li[j] = -1; }

    for (int i = start + tid; i < end; i += 64) {
        float v = s[i];
        if (v > tv[KC-1]) {
            #pragma unroll
            for (int j = KC-1; j >= 1; --j) {
                if (v > tv[j-1])      { tv[j] = tv[j-1]; ti[j] = ti[j-1]; }
                else if (v > tv[j])   { tv[j] = v;       ti[j] = i;       }
            }
            if (v > tv[0]) { tv[0] = v; ti[0] = i; }
        }
        if (v < lv[KC-1]) {
            #pragma unroll
            for (int j = KC-1; j >= 1; --j) {
                if (v < lv[j-1])      { lv[j] = lv[j-1]; li[j] = li[j-1]; }
                else if (v < lv[j])   { lv[j] = v;       li[j] = i;       }
            }
            if (v < lv[0]) { lv[0] = v; li[0] = i; }
        }
    }

    size_t base = ((size_t)b * NSEL1 + r) * 2 * KC;
    for (int rd = 0; rd < KC; ++rd) {
        float v = tv[0]; int who = tid;
        #pragma unroll
        for (int off = 32; off > 0; off >>= 1) {
            float ov = __shfl_down(v, off, 64);
            int ow = __shfl_down(who, off, 64);
            if (ov > v) { v = ov; who = ow; }
        }
        int bwho = __shfl(who, 0, 64);
        if (tid == bwho) {
            cv[base + rd] = tv[0]; ci[base + rd] = ti[0];
            #pragma unroll
            for (int j = 0; j < KC-1; ++j) { tv[j] = tv[j+1]; ti[j] = ti[j+1]; }
            tv[KC-1] = -FLT_MAX;
        }
    }
    for (int rd = 0; rd < KC; ++rd) {
        float v = lv[0]; int who = tid;
        #pragma unroll
        for (int off = 32; off > 0; off >>= 1) {
            float ov = __shfl_down(v, off, 64);
            int ow = __shfl_down(who, off, 64);
            if (ov < v) { v = ov; who = ow; }
        }
        int bwho = __shfl(who, 0, 64);
        if (tid == bwho) {
            cv[base + KC + rd] = lv[0]; ci[base + KC + rd] = li[0];
            #pragma unroll
            for (int j = 0; j < KC-1; ++j) { lv[j] = lv[j+1]; li[j] = li[j+1]; }
            lv[KC-1] = FLT_MAX;
        }
    }
}

// ---------------------------------------------------------------------------
// Kernel 2b: per bag, merge -> global approx top-12/bottom-12 indices.
// ---------------------------------------------------------------------------
__global__ __launch_bounds__(64) void select2_kernel(
    const float* __restrict__ cv, const int* __restrict__ ci,
    int* __restrict__ cand_idx)
{
    const int b = blockIdx.x;
    const int tid = threadIdx.x;

    float tv[KC]; int ti[KC];
    float lv[KC]; int li[KC];
    #pragma unroll
    for (int j = 0; j < KC; ++j) { tv[j] = -FLT_MAX; ti[j] = -1; lv[j] = FLT_MAX; li[j] = -1; }

    for (int c = tid; c < NSEL1 * KC; c += 64) {
        int rr = c / KC, jj = c % KC;
        size_t base = ((size_t)b * NSEL1 + rr) * 2 * KC;
        {
            float v = cv[base + jj]; int idx = ci[base + jj];
            if (v > tv[KC-1]) {
                #pragma unroll
                for (int j = KC-1; j >= 1; --j) {
                    if (v > tv[j-1])      { tv[j] = tv[j-1]; ti[j] = ti[j-1]; }
                    else if (v > tv[j])   { tv[j] = v;       ti[j] = idx;     }
                }
                if (v > tv[0]) { tv[0] = v; ti[0] = idx; }
            }
        }
        {
            float v = cv[base + KC + jj]; int idx = ci[base + KC + jj];
            if (v < lv[KC-1]) {
                #pragma unroll
                for (int j = KC-1; j >= 1; --j) {
                    if (v < lv[j-1])      { lv[j] = lv[j-1]; li[j] = li[j-1]; }
                    else if (v < lv[j])   { lv[j] = v;       li[j] = idx;     }
                }
                if (v < lv[0]) { lv[0] = v; li[0] = idx; }
            }
        }
    }

    for (int rd = 0; rd < KC; ++rd) {
        float v = tv[0]; int who = tid;
        #pragma unroll
        for (int off = 32; off > 0; off >>= 1) {
            float ov = __shfl_down(v, off, 64);
            int ow = __shfl_down(who, off, 64);
            if (ov > v) { v = ov; who = ow; }
        }
        int bwho = __shfl(who, 0, 64);
        if (tid == bwho) {
            cand_idx[b * 2 * KC + rd] = ti[0];
            #pragma unroll
            for (int j = 0; j < KC-1; ++j) { tv[j] = tv[j+1]; ti[j] = ti[j+1]; }
            tv[KC-1] = -FLT_MAX;
        }
    }
    for (int rd = 0; rd < KC; ++rd) {
        float v = lv[0]; int who = tid;
        #pragma unroll
        for (int off = 32; off > 0; off >>= 1) {
            float ov = __shfl_down(v, off, 64);
            int ow = __shfl_down(who, off, 64);
            if (ov < v) { v = ov; who = ow; }
        }
        int bwho = __shfl(who, 0, 64);
        if (tid == bwho) {
            cand_idx[b * 2 * KC + KC + rd] = li[0];
            #pragma unroll
            for (int j = 0; j < KC-1; ++j) { lv[j] = lv[j+1]; li[j] = li[j+1]; }
            lv[KC-1] = FLT_MAX;
        }
    }
}

// ---------------------------------------------------------------------------
// Kernel 3: exact fp32 rescore of each candidate row.
// ---------------------------------------------------------------------------
__global__ __launch_bounds__(256) void rescore_kernel(
    const float* __restrict__ x,
    const float* __restrict__ Wv, const float* __restrict__ bv,
    const float* __restrict__ Wu, const float* __restrict__ bu,
    const float* __restrict__ Ww, const float* __restrict__ bw,
    const int* __restrict__ cand_idx, float* __restrict__ cand_score, int N)
{
    const int j = blockIdx.x, b = blockIdx.y;
    const int tid = threadIdx.x;
    __shared__ float xsr[INPUT_DIM];
    __shared__ float sp[4];

    int idx = cand_idx[b * 2 * KC + j];
    const float* xr = x + ((size_t)b * N + idx) * INPUT_DIM;
    *(float4*)(&xsr[tid * 4]) = *(const float4*)(&xr[tid * 4]);
    __syncthreads();

    const int h = tid >> 1;
    const int isU = tid & 1;
    const float* W = isU ? Wu : Wv;
    float s = 0.f;
    #pragma unroll 8
    for (int k = 0; k < INPUT_DIM; ++k)
        s = fmaf(xsr[k], W[(size_t)k * HIDDEN + h], s);

    float other = __shfl_xor(s, 1, 64);
    float g = 0.f;
    if (!isU) {
        float vv = tanhf(s + bv[h]);
        float uu = 1.0f / (1.0f + expf(-(other + bu[h])));
        g = vv * uu * Ww[h];
    }
    #pragma unroll
    for (int off = 1; off < 64; off <<= 1) g += __shfl_xor(g, off, 64);
    if ((tid & 63) == 0) sp[tid >> 6] = g;
    __syncthreads();
    if (tid == 0)
        cand_score[b * 2 * KC + j] = sp[0] + sp[1] + sp[2] + sp[3] + bw[0];
}

// ---------------------------------------------------------------------------
// Kernel 4: exact top/bottom-10 sets, exact softmax, scatter atten, gather Z.
// ---------------------------------------------------------------------------
__global__ __launch_bounds__(256) void final_kernel(
    const float* __restrict__ x, const int* __restrict__ cand_idx,
    const float* __restrict__ cand_score,
    float* __restrict__ atten, float* __restrict__ Z, int N)
{
    const int b = blockIdx.x;
    const int tid = threadIdx.x;
    __shared__ int fidx[2 * KSEL];
    __shared__ float fw[2 * KSEL];

    if (tid == 0) {
        float cs[2 * KC]; int ciX[2 * KC]; bool used[2 * KC];
        #pragma unroll
        for (int j2 = 0; j2 < 2 * KC; ++j2) {
            cs[j2] = cand_score[b * 2 * KC + j2];
            ciX[j2] = cand_idx[b * 2 * KC + j2];
            used[j2] = false;
        }
        float fs[2 * KSEL];
        for (int r = 0; r < KSEL; ++r) {
            int best = -1; float bvv = -FLT_MAX;
            for (int j2 = 0; j2 < KC; ++j2)
                if (!used[j2] && cs[j2] > bvv) { bvv = cs[j2]; best = j2; }
            used[best] = true; fidx[r] = ciX[best]; fs[r] = bvv;
        }
        for (int r = 0; r < KSEL; ++r) {
            int best = -1; float bvv = FLT_MAX;
            for (int j2 = KC; j2 < 2 * KC; ++j2)
                if (!used[j2] && cs[j2] < bvv) { bvv = cs[j2]; best = j2; }
            used[best] = true; fidx[KSEL + r] = ciX[best]; fs[KSEL + r] = bvv;
        }
        float m = -FLT_MAX;
        for (int j2 = 0; j2 < 2 * KSEL; ++j2) m = fmaxf(m, fs[j2]);
        float e[2 * KSEL], sum = 0.f;
        for (int j2 = 0; j2 < 2 * KSEL; ++j2) { e[j2] = expf(fs[j2] - m); sum += e[j2]; }
        float inv = 1.0f / sum;
        for (int j2 = 0; j2 < 2 * KSEL; ++j2) {
            fw[j2] = e[j2] * inv;
            atten[(size_t)b * N + fidx[j2]] = fw[j2];
        }
    }
    __syncthreads();

    float4 acc = make_float4(0.f, 0.f, 0.f, 0.f);
    #pragma unroll
    for (int j2 = 0; j2 < 2 * KSEL; ++j2) {
        int idx = fidx[j2];
        float wgt = fw[j2];
        const float4* xr = (const float4*)(x + ((size_t)b * N + idx) * INPUT_DIM);
        float4 v = xr[tid];
        acc.x = fmaf(wgt, v.x, acc.x);
        acc.y = fmaf(wgt, v.y, acc.y);
        acc.z = fmaf(wgt, v.z, acc.z);
        acc.w = fmaf(wgt, v.w, acc.w);
    }
    ((float4*)(Z + (size_t)b * INPUT_DIM))[tid] = acc;
}

extern "C" void kernel_launch(void* const* d_in, const int* in_sizes, int n_in,
                              void* d_out, int out_size, void* d_ws, size_t ws_size,
                              hipStream_t stream)
{
    const float* x  = (const float*)d_in[0];
    const float* Wv = (const float*)d_in[1];
    const float* bv = (const float*)d_in[2];
    const float* Wu = (const float*)d_in[3];
    const float* bu = (const float*)d_in[4];
    const float* Ww = (const float*)d_in[5];
    const float* bw = (const float*)d_in[6];

    const int B = 8;
    const int N = in_sizes[0] / (B * INPUT_DIM);   // 50000

    float* Z = (float*)d_out;                              // [B,1024]
    float* atten = (float*)d_out + (size_t)B * INPUT_DIM;  // [B,N]

    // workspace layout
    char* p = (char*)d_ws;
    float* scores = (float*)p;                  p += (size_t)B * N * sizeof(float);
    unsigned short* wp = (unsigned short*)p;    p += (size_t)INPUT_DIM * 256 * sizeof(unsigned short);
    float* cand_v = (float*)p;                  p += (size_t)B * NSEL1 * 2 * KC * sizeof(float);
    int* cand_i = (int*)p;                      p += (size_t)B * NSEL1 * 2 * KC * sizeof(int);
    int* cand_idx = (int*)p;                    p += (size_t)B * 2 * KC * sizeof(int);
    float* cand_score = (float*)p;

    repack_kernel<<<512, 64, 0, stream>>>(Wv, Wu, wp);

    dim3 g1((N + BM - 1) / BM, B);
    scores_kernel<<<g1, STH, 0, stream>>>(x, wp, bv, bu, Ww, bw, scores, atten, N);

    int CH = (N + NSEL1 - 1) / NSEL1;
    dim3 g2(NSEL1, B);
    select1_kernel<<<g2, 64, 0, stream>>>(scores, cand_v, cand_i, N, CH);
    select2_kernel<<<B, 64, 0, stream>>>(cand_v, cand_i, cand_idx);

    dim3 g3(2 * KC, B);
    rescore_kernel<<<g3, 256, 0, stream>>>(x, Wv, bv, Wu, bu, Ww, bw, cand_idx, cand_score, N);
    final_kernel<<<B, 256, 0, stream>>>(x, cand_idx, cand_score, atten, Z, N);
}